// Round 1
// baseline (36.788 us; speedup 1.0000x reference)
//
#include <hip/hip_runtime.h>
#include <math.h>

#define NUM_CLASSES 15
#define NUM_ANCHORS 18
#define NC6 21            // NUM_CLASSES + 6
#define GRID 64
#define BATCH 16

__device__ __forceinline__ float sigmoidf_fast(float v) {
    return 1.0f / (1.0f + __expf(-v));
}

// One block per (b, a, y) group. Group = 21 channels x 64 x-values.
// Input:  in[((b*378 + a*21 + c)*64 + y)*64 + x]   (c stride = 4096 floats)
// Output: out[(b*73728 + a*4096 + y*64 + x)*21 + c] (c contiguous)
__launch_bounds__(256)
__global__ void yolo_layer_kernel(const float* __restrict__ in,
                                  const float* __restrict__ anchors,
                                  float* __restrict__ out) {
    const int gid = blockIdx.x;                 // 0 .. 16*18*64-1
    const int y   = gid & (GRID - 1);
    const int a   = (gid >> 6) % NUM_ANCHORS;
    const int b   = gid / (GRID * NUM_ANCHORS);

    __shared__ float lds[GRID * NC6];           // 1344 floats = 5376 B

    const float aw8 = anchors[a * 3 + 0] * 8.0f;
    const float ah8 = anchors[a * 3 + 1] * 8.0f;
    const float aa  = anchors[a * 3 + 2];

    const int base_in  = (b * (NUM_ANCHORS * NC6) + a * NC6) * (GRID * GRID) + y * GRID;
    const int base_out = gid * (GRID * NC6);

    const int   t  = threadIdx.x;
    const float fy = (float)y;

    // ---- load + transform + LDS transpose scatter: 336 float4 per block ----
    #pragma unroll
    for (int q0 = 0; q0 < 2; ++q0) {
        int q = q0 * 256 + t;
        if (q < (NC6 * GRID / 4)) {             // 336
            int c  = q >> 4;                    // 16 float4 per 64-float row
            int xs = (q & 15) << 2;
            float4 v = *reinterpret_cast<const float4*>(in + base_in + c * (GRID * GRID) + xs);
            float vv[4] = {v.x, v.y, v.z, v.w};
            #pragma unroll
            for (int k = 0; k < 4; ++k) {
                float vk = vv[k];
                float r;
                if (c >= 5) {
                    r = sigmoidf_fast(vk);                                   // conf + cls
                } else if (c == 0) {
                    r = (sigmoidf_fast(vk) * 1.05f - 0.025f + (float)(xs + k)) * 8.0f;
                } else if (c == 1) {
                    r = (sigmoidf_fast(vk) * 1.05f - 0.025f + fy) * 8.0f;
                } else if (c == 2) {
                    r = __expf(vk) * aw8;
                } else if (c == 3) {
                    r = __expf(vk) * ah8;
                } else {                                                     // c == 4
                    r = vk + aa;
                }
                lds[(xs + k) * NC6 + c] = r;
            }
        }
    }
    __syncthreads();

    // ---- contiguous coalesced float4 store of the whole group ----
    #pragma unroll
    for (int q0 = 0; q0 < 2; ++q0) {
        int q = q0 * 256 + t;
        if (q < (NC6 * GRID / 4)) {             // 336
            float4 v = *reinterpret_cast<const float4*>(&lds[q * 4]);
            *reinterpret_cast<float4*>(out + base_out + q * 4) = v;
        }
    }
}

extern "C" void kernel_launch(void* const* d_in, const int* in_sizes, int n_in,
                              void* d_out, int out_size, void* d_ws, size_t ws_size,
                              hipStream_t stream) {
    const float* in      = (const float*)d_in[0];
    const float* anchors = (const float*)d_in[1];
    float* out           = (float*)d_out;

    const int n_groups = BATCH * NUM_ANCHORS * GRID;   // 18432
    yolo_layer_kernel<<<dim3(n_groups), dim3(256), 0, stream>>>(in, anchors, out);
}